// Round 1
// baseline (1903.131 us; speedup 1.0000x reference)
//
#include <hip/hip_runtime.h>

#define Bc 2
#define Lc 2048
#define Dc 1024
#define Hc 16
#define HDc 64
// M = B*L = 4096 rows for all projections

// ---------------------------------------------------------------------------
// Shared 64x64-tile fp32 NT GEMM body: out_tile = A[row0:+64, :] @ W[col0:+64, :]^T
// A: (M,K) row-major, W: (N,K) row-major (torch Linear convention).
// Block = 256 threads, 4x4 micro-tile/thread, K-chunk = 16.
// LDS pad 17: Bs row-varying reads are 2-way aliased (free on gfx950, m136).
// ---------------------------------------------------------------------------
__device__ __forceinline__ void gemm64_body(
    const float* __restrict__ A, const float* __restrict__ W,
    int row0, int col0, int K,
    float (&acc)[4][4], float (*As)[17], float (*Bs)[17])
{
    const int tid = threadIdx.x;
    const int lr  = tid >> 2;          // 0..63 : LDS staging row
    const int lk  = (tid & 3) << 2;    // 0,4,8,12 : k-offset (float4)
    const int tr4 = (tid >> 4) << 2;   // micro-tile row base
    const int tc4 = (tid & 15) << 2;   // micro-tile col base

    for (int k0 = 0; k0 < K; k0 += 16) {
        // issue global loads before the barrier so latency overlaps prior compute
        const float4 av = *(const float4*)&A[(size_t)(row0 + lr) * K + k0 + lk];
        const float4 bv = *(const float4*)&W[(size_t)(col0 + lr) * K + k0 + lk];
        __syncthreads();   // previous iteration's readers are done
        As[lr][lk + 0] = av.x; As[lr][lk + 1] = av.y;
        As[lr][lk + 2] = av.z; As[lr][lk + 3] = av.w;
        Bs[lr][lk + 0] = bv.x; Bs[lr][lk + 1] = bv.y;
        Bs[lr][lk + 2] = bv.z; Bs[lr][lk + 3] = bv.w;
        __syncthreads();
#pragma unroll
        for (int kk = 0; kk < 16; ++kk) {
            float a[4], b[4];
#pragma unroll
            for (int i = 0; i < 4; ++i) a[i] = As[tr4 + i][kk];
#pragma unroll
            for (int j = 0; j < 4; ++j) b[j] = Bs[tc4 + j][kk];
#pragma unroll
            for (int i = 0; i < 4; ++i)
#pragma unroll
                for (int j = 0; j < 4; ++j)
                    acc[i][j] = fmaf(a[i], b[j], acc[i][j]);
        }
    }
}

// ---------------------------------------------------------------------------
// Fused QKV projection. grid = (64, 48): y/16 selects {q,k,v}, y%16 = head
// (a 64-wide col tile aligns exactly with one head since HD=64).
// Output written directly in (B,H,L,HD) layout for the attention kernel.
// ---------------------------------------------------------------------------
__global__ __launch_bounds__(256) void gemm_qkv(
    const float* __restrict__ X,
    const float* __restrict__ Wq, const float* __restrict__ bq,
    const float* __restrict__ Wk, const float* __restrict__ bk,
    const float* __restrict__ Wv, const float* __restrict__ bv,
    float* __restrict__ qo, float* __restrict__ ko, float* __restrict__ vo)
{
    __shared__ float As[64][17];
    __shared__ float Bs[64][17];

    const int sel = blockIdx.y >> 4;                     // 0=q 1=k 2=v (uniform)
    const float* W    = sel == 0 ? Wq : (sel == 1 ? Wk : Wv);
    const float* bias = sel == 0 ? bq : (sel == 1 ? bk : bv);
    float* out        = sel == 0 ? qo : (sel == 1 ? ko : vo);
    const int h    = blockIdx.y & 15;
    const int row0 = blockIdx.x << 6;
    const int col0 = h << 6;

    float acc[4][4] = {};
    gemm64_body(X, W, row0, col0, Dc, acc, As, Bs);

    const int tid = threadIdx.x;
    const int tr4 = (tid >> 4) << 2;
    const int tc4 = (tid & 15) << 2;
    const float4 b4 = *(const float4*)&bias[col0 + tc4];
#pragma unroll
    for (int i = 0; i < 4; ++i) {
        const int r = row0 + tr4 + i;
        const int b = r >> 11;            // r / L
        const int l = r & (Lc - 1);       // r % L
        float4 o;
        o.x = acc[i][0] + b4.x; o.y = acc[i][1] + b4.y;
        o.z = acc[i][2] + b4.z; o.w = acc[i][3] + b4.w;
        *(float4*)&out[(((size_t)(b * Hc + h) * Lc + l) * HDc) + tc4] = o;
    }
}

// ---------------------------------------------------------------------------
// Flash attention, fp32, no score materialization.
// One block = one (b, h, 32-row Q tile). 64 K/V tiles of 32 rows each.
// Online softmax (m,l,alpha in LDS); O accumulator (2 rows x 4 cols) in regs.
// LDS pads: 68 keeps rows 16B-aligned (b128-able); Ps stride 36 same.
// ---------------------------------------------------------------------------
__global__ __launch_bounds__(256) void attn_fa(
    const float* __restrict__ q, const float* __restrict__ k,
    const float* __restrict__ v, float* __restrict__ out)
{
    __shared__ float Qs[32][68];
    __shared__ float Ks[32][68];
    __shared__ float Vs[32][68];
    __shared__ float Ps[32][36];
    __shared__ float m_sh[32], l_sh[32], a_sh[32];

    const int tid = threadIdx.x;
    const int qt = blockIdx.x & 63;                 // L/32 q-tiles
    const int h  = (blockIdx.x >> 6) & (Hc - 1);
    const int b  = blockIdx.x >> 10;
    const int l0 = qt << 5;

    const size_t bh = ((size_t)b * Hc + h) * Lc * HDc;
    const float* qb = q + bh + (size_t)l0 * HDc;
    const float* kb = k + bh;
    const float* vb = v + bh;

    // ---- load Q tile, scale folded in (logits = (q*scale) . k) ----
    {
        const float scale = 0.125f;   // HD^-0.5
#pragma unroll
        for (int it = 0; it < 2; ++it) {
            const int idx = tid + it * 256;       // 0..511 float4 slots
            const int r = idx >> 4;
            const int c = (idx & 15) << 2;
            const float4 t = *(const float4*)&qb[(size_t)r * HDc + c];
            Qs[r][c + 0] = t.x * scale; Qs[r][c + 1] = t.y * scale;
            Qs[r][c + 2] = t.z * scale; Qs[r][c + 3] = t.w * scale;
        }
    }
    if (tid < 32) { m_sh[tid] = -1e30f; l_sh[tid] = 0.0f; }

    const int r0  = (tid >> 4) << 1;   // S/O row pair (0,2,..,30)
    const int c0s = (tid & 15) << 1;   // S col pair
    const int c0o = (tid & 15) << 2;   // O col quad
    float acc[2][4] = {};

    for (int kt = 0; kt < Lc; kt += 32) {
        // prefetch K/V tile into registers before the barrier
        float4 kv[2], vv[2];
#pragma unroll
        for (int it = 0; it < 2; ++it) {
            const int idx = tid + it * 256;
            const int r = idx >> 4;
            const int c = (idx & 15) << 2;
            kv[it] = *(const float4*)&kb[(size_t)(kt + r) * HDc + c];
            vv[it] = *(const float4*)&vb[(size_t)(kt + r) * HDc + c];
        }
        __syncthreads();   // prior PV readers of Ks/Vs/Ps are done
#pragma unroll
        for (int it = 0; it < 2; ++it) {
            const int idx = tid + it * 256;
            const int r = idx >> 4;
            const int c = (idx & 15) << 2;
            Ks[r][c + 0] = kv[it].x; Ks[r][c + 1] = kv[it].y;
            Ks[r][c + 2] = kv[it].z; Ks[r][c + 3] = kv[it].w;
            Vs[r][c + 0] = vv[it].x; Vs[r][c + 1] = vv[it].y;
            Vs[r][c + 2] = vv[it].z; Vs[r][c + 3] = vv[it].w;
        }
        __syncthreads();

        // ---- S = Q . K^T  (2x2 per thread) ----
        float s00 = 0.f, s01 = 0.f, s10 = 0.f, s11 = 0.f;
#pragma unroll
        for (int kd = 0; kd < HDc; ++kd) {
            const float a0 = Qs[r0][kd],      a1 = Qs[r0 + 1][kd];
            const float b0 = Ks[c0s][kd],     b1 = Ks[c0s + 1][kd];
            s00 = fmaf(a0, b0, s00); s01 = fmaf(a0, b1, s01);
            s10 = fmaf(a1, b0, s10); s11 = fmaf(a1, b1, s11);
        }
        Ps[r0][c0s] = s00;     Ps[r0][c0s + 1] = s01;
        Ps[r0 + 1][c0s] = s10; Ps[r0 + 1][c0s + 1] = s11;
        __syncthreads();

        // ---- online softmax row stats (one thread per row) ----
        if (tid < 32) {
            const float mo = m_sh[tid];
            float mt = mo;
#pragma unroll
            for (int c = 0; c < 32; ++c) mt = fmaxf(mt, Ps[tid][c]);
            const float alpha = __expf(mo - mt);
            float s = 0.0f;
#pragma unroll
            for (int c = 0; c < 32; ++c) {
                const float p = __expf(Ps[tid][c] - mt);
                Ps[tid][c] = p;
                s += p;
            }
            m_sh[tid] = mt;
            a_sh[tid] = alpha;
            l_sh[tid] = l_sh[tid] * alpha + s;
        }
        __syncthreads();

        // ---- O = O*alpha + P . V ----
        const float al0 = a_sh[r0], al1 = a_sh[r0 + 1];
#pragma unroll
        for (int j = 0; j < 4; ++j) { acc[0][j] *= al0; acc[1][j] *= al1; }
#pragma unroll
        for (int kk = 0; kk < 32; ++kk) {
            const float p0 = Ps[r0][kk], p1 = Ps[r0 + 1][kk];
            const float4 v4 = *(const float4*)&Vs[kk][c0o];
            acc[0][0] = fmaf(p0, v4.x, acc[0][0]);
            acc[0][1] = fmaf(p0, v4.y, acc[0][1]);
            acc[0][2] = fmaf(p0, v4.z, acc[0][2]);
            acc[0][3] = fmaf(p0, v4.w, acc[0][3]);
            acc[1][0] = fmaf(p1, v4.x, acc[1][0]);
            acc[1][1] = fmaf(p1, v4.y, acc[1][1]);
            acc[1][2] = fmaf(p1, v4.z, acc[1][2]);
            acc[1][3] = fmaf(p1, v4.w, acc[1][3]);
        }
    }

    // ---- finalize: divide by l, write in (B,L,D) layout for the O-proj ----
    const float inv0 = 1.0f / l_sh[r0];
    const float inv1 = 1.0f / l_sh[r0 + 1];
    float* ob = out + ((size_t)(b * Lc + l0) * Dc) + h * HDc;
    float4 o0, o1;
    o0.x = acc[0][0] * inv0; o0.y = acc[0][1] * inv0;
    o0.z = acc[0][2] * inv0; o0.w = acc[0][3] * inv0;
    o1.x = acc[1][0] * inv1; o1.y = acc[1][1] * inv1;
    o1.z = acc[1][2] * inv1; o1.w = acc[1][3] * inv1;
    *(float4*)&ob[(size_t)r0 * Dc + c0o]       = o0;
    *(float4*)&ob[(size_t)(r0 + 1) * Dc + c0o] = o1;
}

// ---------------------------------------------------------------------------
// Output projection: d_out = attn @ Wo^T + bo, row-major (B,L,D).
// ---------------------------------------------------------------------------
__global__ __launch_bounds__(256) void gemm_o(
    const float* __restrict__ X, const float* __restrict__ Wo,
    const float* __restrict__ bo, float* __restrict__ out)
{
    __shared__ float As[64][17];
    __shared__ float Bs[64][17];
    const int row0 = blockIdx.x << 6;
    const int col0 = blockIdx.y << 6;

    float acc[4][4] = {};
    gemm64_body(X, Wo, row0, col0, Dc, acc, As, Bs);

    const int tid = threadIdx.x;
    const int tr4 = (tid >> 4) << 2;
    const int tc4 = (tid & 15) << 2;
    const float4 b4 = *(const float4*)&bo[col0 + tc4];
#pragma unroll
    for (int i = 0; i < 4; ++i) {
        const int r = row0 + tr4 + i;
        float4 o;
        o.x = acc[i][0] + b4.x; o.y = acc[i][1] + b4.y;
        o.z = acc[i][2] + b4.z; o.w = acc[i][3] + b4.w;
        *(float4*)&out[(size_t)r * Dc + col0 + tc4] = o;
    }
}

extern "C" void kernel_launch(void* const* d_in, const int* in_sizes, int n_in,
                              void* d_out, int out_size, void* d_ws, size_t ws_size,
                              hipStream_t stream)
{
    const float* query = (const float*)d_in[0];
    const float* Wq = (const float*)d_in[1];
    const float* bq = (const float*)d_in[2];
    const float* Wk = (const float*)d_in[3];
    const float* bk = (const float*)d_in[4];
    const float* Wv = (const float*)d_in[5];
    const float* bv = (const float*)d_in[6];
    const float* Wo = (const float*)d_in[7];
    const float* bo = (const float*)d_in[8];

    // workspace layout: q | k | v | attn, each B*H*L*HD = 4,194,304 floats
    // (total 67.1 MB; every element fully overwritten each call -> poison-safe)
    float* ws = (float*)d_ws;
    const size_t per = (size_t)Bc * Hc * Lc * HDc;
    float* q_ws = ws;
    float* k_ws = ws + per;
    float* v_ws = ws + 2 * per;
    float* a_ws = ws + 3 * per;

    gemm_qkv<<<dim3(64, 48), 256, 0, stream>>>(query, Wq, bq, Wk, bk, Wv, bv,
                                               q_ws, k_ws, v_ws);
    attn_fa<<<dim3(2048), 256, 0, stream>>>(q_ws, k_ws, v_ws, a_ws);
    gemm_o<<<dim3(64, 16), 256, 0, stream>>>(a_ws, Wo, bo, (float*)d_out);
}

// Round 2
// 290.081 us; speedup vs baseline: 6.5607x; 6.5607x over previous
//
#include <hip/hip_runtime.h>

// B=2, L=2048, D=1024, H=16, HD=64.  All matmuls via bf16 MFMA (fp32 accum).
#define Bc 2
#define Lc 2048
#define Dc 1024
#define Hc 16
#define HDc 64
#define LOG2E 1.44269504088896340736f

typedef __bf16 bf16x8 __attribute__((ext_vector_type(8)));
typedef float f32x4 __attribute__((ext_vector_type(4)));
typedef unsigned short u16;
typedef unsigned int u32;

// fp32 -> bf16 round-to-nearest-even
__device__ __forceinline__ u16 f2bf(float x) {
    union { float f; u32 u; } c; c.f = x;
    u32 u = c.u + 0x7fffu + ((c.u >> 16) & 1u);
    return (u16)(u >> 16);
}

// async global->LDS, 16B/lane. LDS dest = wave-uniform base + lane*16 (m104).
__device__ __forceinline__ void g2l16(const void* g, void* l) {
    __builtin_amdgcn_global_load_lds(
        (const __attribute__((address_space(1))) void*)g,
        (__attribute__((address_space(3))) void*)l, 16, 0, 0);
}

// ---------------------------------------------------------------------------
// cast fp32 -> bf16: query (4096x1024) + Wq/Wk/Wv/Wo (1024x1024 each)
// ---------------------------------------------------------------------------
__global__ __launch_bounds__(256) void cast_bf16(
    const float* __restrict__ x,
    const float* __restrict__ wq, const float* __restrict__ wk,
    const float* __restrict__ wv, const float* __restrict__ wo,
    u16* __restrict__ xb, u16* __restrict__ wqb, u16* __restrict__ wkb,
    u16* __restrict__ wvb, u16* __restrict__ wob)
{
    const int i = blockIdx.x * 256 + threadIdx.x;   // float4 index
    const float* s; u16* d; int off;
    if (i < 1048576) { s = x; d = xb; off = i; }
    else {
        const int j = i - 1048576;
        const int sel = j >> 18;            // 0..3
        off = j & 262143;
        s = sel == 0 ? wq : sel == 1 ? wk : sel == 2 ? wv : wo;
        d = sel == 0 ? wqb : sel == 1 ? wkb : sel == 2 ? wvb : wob;
    }
    const float4 f = ((const float4*)s)[off];
    ushort4 o;
    o.x = f2bf(f.x); o.y = f2bf(f.y); o.z = f2bf(f.z); o.w = f2bf(f.w);
    ((ushort4*)d)[off] = o;
}

// ---------------------------------------------------------------------------
// m97-style 128x128-tile bf16 NT GEMM body (both operands K-contiguous).
// 4 waves, each owns a 64x64 quadrant = 4x4 tiles of mfma_f32_16x16x32_bf16.
// LDS: A-tile [128][32] bf16 + B-tile [128][32] bf16, staged via g2l16.
// ---------------------------------------------------------------------------
__device__ __forceinline__ void gemm128_body(
    const u16* __restrict__ A, const u16* __restrict__ Bm,
    int row0, int col0, int K,
    f32x4 (&acc)[4][4], u16* As, u16* Bs)
{
    const int tid  = threadIdx.x;
    const int w    = tid >> 6;
    const int lane = tid & 63;
    const int l15  = lane & 15, quad = lane >> 4;
    const int srow = lane >> 2;            // 0..15 row within a 16-row chunk
    const int scol = (lane & 3) << 3;      // 0,8,16,24 bf16 elems
    const int wm   = (w & 1) << 6, wn = (w >> 1) << 6;

    for (int k0 = 0; k0 < K; k0 += 32) {
        __syncthreads();                   // prior tile's readers done
#pragma unroll
        for (int s = 0; s < 2; ++s) {      // wave w stages rows [w*32, w*32+32)
            const int r = w * 32 + s * 16;
            g2l16(&A [(size_t)(row0 + r + srow) * K + k0 + scol], &As[r * 32]);
            g2l16(&Bm[(size_t)(col0 + r + srow) * K + k0 + scol], &Bs[r * 32]);
        }
        __syncthreads();                   // vmcnt(0) drain before use

        bf16x8 af[4], bf[4];
#pragma unroll
        for (int i = 0; i < 4; ++i)
            af[i] = *(const bf16x8*)&As[(wm + i * 16 + l15) * 32 + quad * 8];
#pragma unroll
        for (int j = 0; j < 4; ++j)
            bf[j] = *(const bf16x8*)&Bs[(wn + j * 16 + l15) * 32 + quad * 8];
#pragma unroll
        for (int i = 0; i < 4; ++i)
#pragma unroll
            for (int j = 0; j < 4; ++j)
                acc[i][j] = __builtin_amdgcn_mfma_f32_16x16x32_bf16(
                    af[i], bf[j], acc[i][j], 0, 0, 0);
    }
}

// ---------------------------------------------------------------------------
// Fused QKV projection. grid (32, 8, 3): z selects {q,k,v}.
// q: *0.125 (HD^-0.5, exact in bf16), layout (B,H,L,HD)
// k: layout (B,H,L,HD);  v: TRANSPOSED layout (B,H,HD,L) for the PV MFMA.
// ---------------------------------------------------------------------------
__global__ __launch_bounds__(256) void gemm_qkv_bf16(
    const u16* __restrict__ Xb,
    const u16* __restrict__ Wqb, const u16* __restrict__ Wkb, const u16* __restrict__ Wvb,
    const float* __restrict__ bq, const float* __restrict__ bk, const float* __restrict__ bv,
    u16* __restrict__ qo, u16* __restrict__ ko, u16* __restrict__ vto)
{
    __shared__ u16 As[128 * 32];
    __shared__ u16 Bs[128 * 32];

    const int z = blockIdx.z;
    const u16*   W    = z == 0 ? Wqb : (z == 1 ? Wkb : Wvb);
    const float* bias = z == 0 ? bq  : (z == 1 ? bk  : bv);
    const int row0 = blockIdx.x << 7;
    const int col0 = blockIdx.y << 7;

    f32x4 acc[4][4];
#pragma unroll
    for (int i = 0; i < 4; ++i)
#pragma unroll
        for (int j = 0; j < 4; ++j)
#pragma unroll
            for (int r = 0; r < 4; ++r) acc[i][j][r] = 0.0f;

    gemm128_body(Xb, W, row0, col0, Dc, acc, As, Bs);

    const int tid = threadIdx.x;
    const int w = tid >> 6, lane = tid & 63;
    const int l15 = lane & 15, quad = lane >> 4;
    const int wm = (w & 1) << 6, wn = (w >> 1) << 6;

#pragma unroll
    for (int j = 0; j < 4; ++j) {
        const int n  = col0 + wn + j * 16 + l15;
        const float bj = bias[n];
        const int hh = n >> 6, hd = n & 63;
#pragma unroll
        for (int i = 0; i < 4; ++i)
#pragma unroll
            for (int r = 0; r < 4; ++r) {
                const int m  = row0 + wm + i * 16 + quad * 4 + r;
                const int bb = m >> 11, ll = m & (Lc - 1);
                const float val = acc[i][j][r] + bj;
                if (z == 0)
                    qo[(((size_t)(bb * Hc + hh) * Lc + ll) << 6) + hd] = f2bf(val * 0.125f);
                else if (z == 1)
                    ko[(((size_t)(bb * Hc + hh) * Lc + ll) << 6) + hd] = f2bf(val);
                else
                    vto[(((size_t)(bb * Hc + hh) * HDc + hd) << 11) + ll] = f2bf(val);
            }
    }
}

// ---------------------------------------------------------------------------
// Flash attention on MFMA. Block = 4 waves = 64 Q rows; wave owns 16 rows.
// K-tiles of 64 keys; K and Vt staged in 32-wide k/j panels (64B LDS rows,
// the m97 conflict pattern). Online softmax in registers (shfl_xor over the
// 16 lanes of a quad = one C-layout row group). P goes C->A layout through
// per-wave LDS (m120 pattern).
// ---------------------------------------------------------------------------
__global__ __launch_bounds__(256) void attn_mfma(
    const u16* __restrict__ q, const u16* __restrict__ k,
    const u16* __restrict__ vt, u16* __restrict__ out)
{
    __shared__ u16 Ks[2][64 * 32];       // [k-panel][key j][32 k]
    __shared__ u16 Vs[2][64 * 32];       // [j-panel][d][32 j]
    __shared__ u16 Ps[4][2][16 * 32];    // [wave][j-panel][m][32 j]

    const int tid = threadIdx.x;
    const int w = tid >> 6, lane = tid & 63;
    const int l15 = lane & 15, quad = lane >> 4;
    const int qt = blockIdx.x & 31;
    const int h  = (blockIdx.x >> 5) & (Hc - 1);
    const int b  = blockIdx.x >> 9;
    const int l0 = qt << 6;

    const size_t bh = (size_t)(b * Hc + h) * (Lc * HDc);
    const u16* qb = q  + bh;
    const u16* kb = k  + bh;
    const u16* vb = vt + bh;             // [HD][L]

    // Q fragments for the whole kernel (A-operand: A[m=l15][k=quad*8+j])
    bf16x8 qf0, qf1;
    {
        const size_t qrow = (size_t)(l0 + w * 16 + l15) * HDc;
        qf0 = *(const bf16x8*)&qb[qrow + quad * 8];
        qf1 = *(const bf16x8*)&qb[qrow + 32 + quad * 8];
    }

    f32x4 oacc[4];
    float m_i[4], l_i[4];
#pragma unroll
    for (int r = 0; r < 4; ++r) {
        m_i[r] = -1e30f; l_i[r] = 0.0f;
#pragma unroll
        for (int dt = 0; dt < 4; ++dt) oacc[dt][r] = 0.0f;
    }

    for (int kt = 0; kt < Lc; kt += 64) {
        __syncthreads();
        // stage K (8KB) + Vt (8KB): 8 chunks of 1KB each array, 2 per wave
#pragma unroll
        for (int s = 0; s < 2; ++s) {
            const int c  = w * 2 + s;        // 0..7
            const int p  = c >> 2;           // panel
            const int r0 = (c & 3) << 4;     // 16-row chunk
            const int row = r0 + (lane >> 2);
            const int col = p * 32 + (lane & 3) * 8;
            g2l16(&kb[(size_t)(kt + row) * HDc + col], &Ks[p][r0 * 32]);
            g2l16(&vb[(size_t)row * Lc + kt + col],    &Vs[p][r0 * 32]);
        }
        __syncthreads();

        // ---- S = Q.K^T (16 x 64 per wave), scaled into log2 domain ----
        f32x4 st[4];
#pragma unroll
        for (int jt = 0; jt < 4; ++jt) {
            const bf16x8 b0 = *(const bf16x8*)&Ks[0][(jt * 16 + l15) * 32 + quad * 8];
            const bf16x8 b1 = *(const bf16x8*)&Ks[1][(jt * 16 + l15) * 32 + quad * 8];
            f32x4 z = {0.0f, 0.0f, 0.0f, 0.0f};
            z = __builtin_amdgcn_mfma_f32_16x16x32_bf16(qf0, b0, z, 0, 0, 0);
            st[jt] = __builtin_amdgcn_mfma_f32_16x16x32_bf16(qf1, b1, z, 0, 0, 0);
#pragma unroll
            for (int r = 0; r < 4; ++r) st[jt][r] *= LOG2E;
        }

        // ---- online softmax: rows m = quad*4+r live on the quad's 16 lanes
        float al[4];
#pragma unroll
        for (int r = 0; r < 4; ++r) {
            float v = fmaxf(fmaxf(st[0][r], st[1][r]), fmaxf(st[2][r], st[3][r]));
#pragma unroll
            for (int mk = 1; mk < 16; mk <<= 1) v = fmaxf(v, __shfl_xor(v, mk));
            const float mn = fmaxf(m_i[r], v);
            al[r] = exp2f(m_i[r] - mn);
            m_i[r] = mn;
        }
        float rs[4] = {0.f, 0.f, 0.f, 0.f};
        u16 pb[4][4];
#pragma unroll
        for (int jt = 0; jt < 4; ++jt)
#pragma unroll
            for (int r = 0; r < 4; ++r) {
                const float p = exp2f(st[jt][r] - m_i[r]);
                rs[r] += p;
                pb[jt][r] = f2bf(p);
            }
#pragma unroll
        for (int r = 0; r < 4; ++r) {
            float v = rs[r];
#pragma unroll
            for (int mk = 1; mk < 16; mk <<= 1) v += __shfl_xor(v, mk);
            l_i[r] = l_i[r] * al[r] + v;
#pragma unroll
            for (int dt = 0; dt < 4; ++dt) oacc[dt][r] *= al[r];
        }

        // ---- P: C-layout regs -> A-layout via per-wave LDS ----
#pragma unroll
        for (int jt = 0; jt < 4; ++jt) {
            const int pan = jt >> 1;
            const int jc  = (jt & 1) * 16 + l15;
#pragma unroll
            for (int r = 0; r < 4; ++r)
                Ps[w][pan][(quad * 4 + r) * 32 + jc] = pb[jt][r];
        }
        const bf16x8 pf0 = *(const bf16x8*)&Ps[w][0][l15 * 32 + quad * 8];
        const bf16x8 pf1 = *(const bf16x8*)&Ps[w][1][l15 * 32 + quad * 8];

        // ---- O += P.V  (B-operand: Vt panels, B[n=d][k=j]) ----
#pragma unroll
        for (int dt = 0; dt < 4; ++dt) {
            const bf16x8 v0 = *(const bf16x8*)&Vs[0][(dt * 16 + l15) * 32 + quad * 8];
            const bf16x8 v1 = *(const bf16x8*)&Vs[1][(dt * 16 + l15) * 32 + quad * 8];
            oacc[dt] = __builtin_amdgcn_mfma_f32_16x16x32_bf16(pf0, v0, oacc[dt], 0, 0, 0);
            oacc[dt] = __builtin_amdgcn_mfma_f32_16x16x32_bf16(pf1, v1, oacc[dt], 0, 0, 0);
        }
    }

    // ---- finalize: /l, write bf16 in (B,L,D) for the O-projection ----
#pragma unroll
    for (int r = 0; r < 4; ++r) {
        const float inv = 1.0f / l_i[r];
        const int l = l0 + w * 16 + quad * 4 + r;
        const size_t base = ((size_t)(b * Lc + l)) * Dc + h * HDc;
#pragma unroll
        for (int dt = 0; dt < 4; ++dt)
            out[base + dt * 16 + l15] = f2bf(oacc[dt][r] * inv);
    }
}

// ---------------------------------------------------------------------------
// Output projection: d_out(fp32) = attn(bf16) @ Wo^T + bo. grid (32, 8).
// ---------------------------------------------------------------------------
__global__ __launch_bounds__(256) void gemm_o_bf16(
    const u16* __restrict__ Ab, const u16* __restrict__ Wob,
    const float* __restrict__ bo, float* __restrict__ out)
{
    __shared__ u16 As[128 * 32];
    __shared__ u16 Bs[128 * 32];
    const int row0 = blockIdx.x << 7;
    const int col0 = blockIdx.y << 7;

    f32x4 acc[4][4];
#pragma unroll
    for (int i = 0; i < 4; ++i)
#pragma unroll
        for (int j = 0; j < 4; ++j)
#pragma unroll
            for (int r = 0; r < 4; ++r) acc[i][j][r] = 0.0f;

    gemm128_body(Ab, Wob, row0, col0, Dc, acc, As, Bs);

    const int tid = threadIdx.x;
    const int w = tid >> 6, lane = tid & 63;
    const int l15 = lane & 15, quad = lane >> 4;
    const int wm = (w & 1) << 6, wn = (w >> 1) << 6;

#pragma unroll
    for (int j = 0; j < 4; ++j) {
        const int n = col0 + wn + j * 16 + l15;
        const float bj = bo[n];
#pragma unroll
        for (int i = 0; i < 4; ++i)
#pragma unroll
            for (int r = 0; r < 4; ++r) {
                const int m = row0 + wm + i * 16 + quad * 4 + r;
                out[(size_t)m * Dc + n] = acc[i][j][r] + bj;
            }
    }
}

extern "C" void kernel_launch(void* const* d_in, const int* in_sizes, int n_in,
                              void* d_out, int out_size, void* d_ws, size_t ws_size,
                              hipStream_t stream)
{
    const float* query = (const float*)d_in[0];
    const float* Wq = (const float*)d_in[1];
    const float* bq = (const float*)d_in[2];
    const float* Wk = (const float*)d_in[3];
    const float* bk = (const float*)d_in[4];
    const float* Wv = (const float*)d_in[5];
    const float* bv = (const float*)d_in[6];
    const float* Wo = (const float*)d_in[7];
    const float* bo = (const float*)d_in[8];

    // ws layout (u16 elems): xb 4.19M | wq/wk/wv/wo 1.05M ea | q | k | vt | a
    u16* ws = (u16*)d_ws;
    const size_t nX = (size_t)Bc * Lc * Dc;      // 4,194,304
    const size_t nW = (size_t)Dc * Dc;           // 1,048,576
    u16* xb  = ws;
    u16* wqb = xb + nX;
    u16* wkb = wqb + nW;
    u16* wvb = wkb + nW;
    u16* wob = wvb + nW;
    u16* q_w = wob + nW;
    u16* k_w = q_w + nX;
    u16* vt_w = k_w + nX;
    u16* a_w = vt_w + nX;

    cast_bf16<<<dim3(8192), 256, 0, stream>>>(query, Wq, Wk, Wv, Wo,
                                              xb, wqb, wkb, wvb, wob);
    gemm_qkv_bf16<<<dim3(32, 8, 3), 256, 0, stream>>>(xb, wqb, wkb, wvb,
                                                      bq, bk, bv, q_w, k_w, vt_w);
    attn_mfma<<<dim3(1024), 256, 0, stream>>>(q_w, k_w, vt_w, a_w);
    gemm_o_bf16<<<dim3(32, 8), 256, 0, stream>>>(a_w, wob, bo, (float*)d_out);
}

// Round 3
// 243.509 us; speedup vs baseline: 7.8154x; 1.1913x over previous
//
#include <hip/hip_runtime.h>

// B=2, L=2048, D=1024, H=16, HD=64.  All matmuls via bf16 MFMA (fp32 accum).
#define Bc 2
#define Lc 2048
#define Dc 1024
#define Hc 16
#define HDc 64
#define LOG2E 1.44269504088896340736f

typedef __bf16 bf16x8 __attribute__((ext_vector_type(8)));
typedef __bf16 bf16x2 __attribute__((ext_vector_type(2)));
typedef float f32x4 __attribute__((ext_vector_type(4)));
typedef unsigned short u16;
typedef unsigned int u32;
typedef unsigned long long u64;

// fp32 -> bf16 round-to-nearest-even
__device__ __forceinline__ u16 f2bf(float x) {
    union { float f; u32 u; } c; c.f = x;
    u32 u = c.u + 0x7fffu + ((c.u >> 16) & 1u);
    return (u16)(u >> 16);
}

// pack two fp32 -> bf16x2 in one u32 (low = a)
__device__ __forceinline__ u32 pkbf(float a, float b) {
#if __has_builtin(__builtin_amdgcn_cvt_pk_bf16_f32)
    union { bf16x2 v; u32 u; } c;
    c.v = __builtin_amdgcn_cvt_pk_bf16_f32(a, b);
    return c.u;
#else
    return (u32)f2bf(a) | ((u32)f2bf(b) << 16);
#endif
}

// async global->LDS, 16B/lane. LDS dest = wave-uniform base + lane*16 (m104).
__device__ __forceinline__ void g2l16(const void* g, void* l) {
    __builtin_amdgcn_global_load_lds(
        (const __attribute__((address_space(1))) void*)g,
        (__attribute__((address_space(3))) void*)l, 16, 0, 0);
}

// ---------------------------------------------------------------------------
// cast fp32 -> bf16: query (4096x1024) + Wq/Wk/Wv/Wo (1024x1024 each)
// ---------------------------------------------------------------------------
__global__ __launch_bounds__(256) void cast_bf16(
    const float* __restrict__ x,
    const float* __restrict__ wq, const float* __restrict__ wk,
    const float* __restrict__ wv, const float* __restrict__ wo,
    u16* __restrict__ xb, u16* __restrict__ wqb, u16* __restrict__ wkb,
    u16* __restrict__ wvb, u16* __restrict__ wob)
{
    const int i = blockIdx.x * 256 + threadIdx.x;   // float4 index
    const float* s; u16* d; int off;
    if (i < 1048576) { s = x; d = xb; off = i; }
    else {
        const int j = i - 1048576;
        const int sel = j >> 18;            // 0..3
        off = j & 262143;
        s = sel == 0 ? wq : sel == 1 ? wk : sel == 2 ? wv : wo;
        d = sel == 0 ? wqb : sel == 1 ? wkb : sel == 2 ? wvb : wob;
    }
    const float4 f = ((const float4*)s)[off];
    ushort4 o;
    o.x = f2bf(f.x); o.y = f2bf(f.y); o.z = f2bf(f.z); o.w = f2bf(f.w);
    ((ushort4*)d)[off] = o;
}

// ---------------------------------------------------------------------------
// m97-style 128x128-tile bf16 NT GEMM body (both operands K-contiguous).
// 4 waves, each owns a 64x64 quadrant = 4x4 tiles of mfma_f32_16x16x32_bf16.
// ---------------------------------------------------------------------------
__device__ __forceinline__ void gemm128_body(
    const u16* __restrict__ A, const u16* __restrict__ Bm,
    int row0, int col0, int K,
    f32x4 (&acc)[4][4], u16* As, u16* Bs)
{
    const int tid  = threadIdx.x;
    const int w    = tid >> 6;
    const int lane = tid & 63;
    const int l15  = lane & 15, quad = lane >> 4;
    const int srow = lane >> 2;            // 0..15 row within a 16-row chunk
    const int scol = (lane & 3) << 3;      // 0,8,16,24 bf16 elems
    const int wm   = (w & 1) << 6, wn = (w >> 1) << 6;

    for (int k0 = 0; k0 < K; k0 += 32) {
        __syncthreads();                   // prior tile's readers done
#pragma unroll
        for (int s = 0; s < 2; ++s) {      // wave w stages rows [w*32, w*32+32)
            const int r = w * 32 + s * 16;
            g2l16(&A [(size_t)(row0 + r + srow) * K + k0 + scol], &As[r * 32]);
            g2l16(&Bm[(size_t)(col0 + r + srow) * K + k0 + scol], &Bs[r * 32]);
        }
        __syncthreads();                   // vmcnt(0) drain before use

        bf16x8 af[4], bf[4];
#pragma unroll
        for (int i = 0; i < 4; ++i)
            af[i] = *(const bf16x8*)&As[(wm + i * 16 + l15) * 32 + quad * 8];
#pragma unroll
        for (int j = 0; j < 4; ++j)
            bf[j] = *(const bf16x8*)&Bs[(wn + j * 16 + l15) * 32 + quad * 8];
#pragma unroll
        for (int i = 0; i < 4; ++i)
#pragma unroll
            for (int j = 0; j < 4; ++j)
                acc[i][j] = __builtin_amdgcn_mfma_f32_16x16x32_bf16(
                    af[i], bf[j], acc[i][j], 0, 0, 0);
    }
}

// ---------------------------------------------------------------------------
// Fused QKV projection. grid (32, 8, 3): z selects {q,k,v}.
// q: *(0.125*log2e) folded (exp2-domain softmax), layout (B,H,L,HD)
// k: layout (B,H,L,HD)
// v: z=2 computes Wv @ X^T (operands swapped) so the TRANSPOSED (B,H,HD,L)
//    store is lane-coalesced instead of a 4KB-stride scatter.
// ---------------------------------------------------------------------------
__global__ __launch_bounds__(256) void gemm_qkv_bf16(
    const u16* __restrict__ Xb,
    const u16* __restrict__ Wqb, const u16* __restrict__ Wkb, const u16* __restrict__ Wvb,
    const float* __restrict__ bq, const float* __restrict__ bk, const float* __restrict__ bv,
    u16* __restrict__ qo, u16* __restrict__ ko, u16* __restrict__ vto)
{
    __shared__ __attribute__((aligned(16))) u16 As[128 * 32];
    __shared__ __attribute__((aligned(16))) u16 Bs[128 * 32];

    const int z = blockIdx.z;
    const int tid = threadIdx.x;
    const int w = tid >> 6, lane = tid & 63;
    const int l15 = lane & 15, quad = lane >> 4;
    const int wm = (w & 1) << 6, wn = (w >> 1) << 6;

    f32x4 acc[4][4];
#pragma unroll
    for (int i = 0; i < 4; ++i)
#pragma unroll
        for (int j = 0; j < 4; ++j)
#pragma unroll
            for (int r = 0; r < 4; ++r) acc[i][j][r] = 0.0f;

    if (z == 2) {
        // ---- V^T path: A = Wv (rows = out-feature), B = X (rows = tokens) ----
        const int row0 = blockIdx.y << 7;      // Wv rows (0..1023)
        const int col0 = blockIdx.x << 7;      // X rows  (0..4095)
        gemm128_body(Wvb, Xb, row0, col0, Dc, acc, As, Bs);

        float bvv[4][4];
#pragma unroll
        for (int i = 0; i < 4; ++i)
#pragma unroll
            for (int r = 0; r < 4; ++r)
                bvv[i][r] = bv[row0 + wm + i * 16 + quad * 4 + r];
#pragma unroll
        for (int j = 0; j < 4; ++j) {
            const int mcol = col0 + wn + j * 16 + l15;    // token index
            const int bb = mcol >> 11, ll = mcol & (Lc - 1);
#pragma unroll
            for (int i = 0; i < 4; ++i)
#pragma unroll
                for (int r = 0; r < 4; ++r) {
                    const int nrow = row0 + wm + i * 16 + quad * 4 + r; // feature
                    const int hh = nrow >> 6, hd = nrow & 63;
                    vto[(((size_t)(bb * Hc + hh) * HDc + hd) << 11) + ll] =
                        f2bf(acc[i][j][r] + bvv[i][r]);
                }
        }
        return;
    }

    // ---- q/k path ----
    const u16*   W    = z == 0 ? Wqb : Wkb;
    const float* bias = z == 0 ? bq  : bk;
    const int row0 = blockIdx.x << 7;
    const int col0 = blockIdx.y << 7;
    gemm128_body(Xb, W, row0, col0, Dc, acc, As, Bs);

    const float qs = 0.125f * LOG2E;   // HD^-0.5 * log2(e)
#pragma unroll
    for (int j = 0; j < 4; ++j) {
        const int n  = col0 + wn + j * 16 + l15;
        const float bj = bias[n];
        const int hh = n >> 6, hd = n & 63;
#pragma unroll
        for (int i = 0; i < 4; ++i)
#pragma unroll
            for (int r = 0; r < 4; ++r) {
                const int m  = row0 + wm + i * 16 + quad * 4 + r;
                const int bb = m >> 11, ll = m & (Lc - 1);
                const float val = acc[i][j][r] + bj;
                const size_t idx = (((size_t)(bb * Hc + hh) * Lc + ll) << 6) + hd;
                if (z == 0) qo[idx] = f2bf(val * qs);
                else        ko[idx] = f2bf(val);
            }
    }
}

// ---------------------------------------------------------------------------
// Flash attention, S^T formulation. Block = 2 waves; wave owns 32 Q rows
// (2 m-tiles). Per 128-key tile:
//   S^T = K.Q^T  (C-layout: col=lane&15 = q-row m, row=quad*4+reg = key j)
//   -> row stats are in-lane + 2 shfl_xor; P exits directly in the PV
//      B-operand layout (no LDS round-trip);  O^T += V^T.P^T.
// K/V staged via global_load_lds with a 16B-unit XOR swizzle on the GLOBAL
// source (LDS dest is lane-fixed) so V b64 frag reads hit the LDS BW floor.
// ---------------------------------------------------------------------------
__global__ __launch_bounds__(128, 2) void attn_mfma(
    const u16* __restrict__ q, const u16* __restrict__ k,
    const u16* __restrict__ vt, u16* __restrict__ out)
{
    __shared__ __attribute__((aligned(16))) u16 Ks[2][128 * 32]; // [d-panel][j][32 d]
    __shared__ __attribute__((aligned(16))) u16 Vs[4][64 * 32];  // [j-panel][d][32 j]

    const int tid = threadIdx.x;
    const int w = tid >> 6, lane = tid & 63;
    const int l15 = lane & 15, quad = lane >> 4;
    const int qt = blockIdx.x & 31;
    const int h  = (blockIdx.x >> 5) & (Hc - 1);
    const int b  = blockIdx.x >> 9;
    const int l0 = qt << 6;

    const size_t bh = (size_t)(b * Hc + h) * (Lc * HDc);
    const u16* qb = q  + bh;
    const u16* kb = k  + bh;
    const u16* vb = vt + bh;             // [HD][L]

    // Q B-operand fragments (n = m-row = l15, k = quad*8+i), whole kernel
    bf16x8 qf[2][2];
#pragma unroll
    for (int mt = 0; mt < 2; ++mt) {
        const size_t row = (size_t)(l0 + w * 32 + mt * 16 + l15) * HDc;
        qf[mt][0] = *(const bf16x8*)&qb[row + quad * 8];
        qf[mt][1] = *(const bf16x8*)&qb[row + 32 + quad * 8];
    }

    const int srow  = lane >> 2;         // staging row within 16-row group
    const int sunit = lane & 3;          // staging 16B unit within 64B row

    f32x4 oacc[2][4];
    float m_i[2], l_i[2];
#pragma unroll
    for (int mt = 0; mt < 2; ++mt) {
        m_i[mt] = -1e30f; l_i[mt] = 0.0f;
#pragma unroll
        for (int dt = 0; dt < 4; ++dt)
#pragma unroll
            for (int r = 0; r < 4; ++r) oacc[mt][dt][r] = 0.0f;
    }

    for (int kt = 0; kt < Lc; kt += 128) {
        __syncthreads();
        // stage K (16KB) + V (16KB); 16 chunks each, 8 per wave
#pragma unroll
        for (int i = 0; i < 8; ++i) {
            const int s = w * 8 + i;
            {   // K: panel p (32 d), 16-row group g; swizzled source unit
                const int p = s >> 3, g = s & 7;
                const int row = g * 16 + srow;                    // key j 0..127
                g2l16(&kb[(size_t)(kt + row) * HDc + p * 32 +
                          ((sunit ^ ((row >> 1) & 3)) << 3)],
                      &Ks[p][g * 512]);
            }
            {   // V: panel p (32 j), 16-row group g over d
                const int p = s >> 2, g = s & 3;
                const int row = g * 16 + srow;                    // d 0..63
                g2l16(&vb[(size_t)row * Lc + kt + p * 32 +
                          ((sunit ^ ((row >> 1) & 3)) << 3)],
                      &Vs[p][g * 512]);
            }
        }
        __syncthreads();

        // ---- S^T = K.Q^T : 8 j-tiles x 2 m-tiles ----
        f32x4 st[2][8];
#pragma unroll
        for (int t = 0; t < 8; ++t) {
            const int j   = t * 16 + l15;
            const int off = j * 32 + ((quad ^ ((j >> 1) & 3)) << 3);
            const bf16x8 kf0 = *(const bf16x8*)&Ks[0][off];
            const bf16x8 kf1 = *(const bf16x8*)&Ks[1][off];
#pragma unroll
            for (int mt = 0; mt < 2; ++mt) {
                f32x4 z = {0.0f, 0.0f, 0.0f, 0.0f};
                z = __builtin_amdgcn_mfma_f32_16x16x32_bf16(kf0, qf[mt][0], z, 0, 0, 0);
                st[mt][t] = __builtin_amdgcn_mfma_f32_16x16x32_bf16(kf1, qf[mt][1], z, 0, 0, 0);
            }
        }

        // ---- online softmax (log2 domain; scale*log2e folded into q) ----
        u32 pk[2][8][2];
#pragma unroll
        for (int mt = 0; mt < 2; ++mt) {
            f32x4 vm = st[mt][0];
#pragma unroll
            for (int t = 1; t < 8; ++t)
#pragma unroll
                for (int r = 0; r < 4; ++r) vm[r] = fmaxf(vm[r], st[mt][t][r]);
            float mx = fmaxf(fmaxf(vm[0], vm[1]), fmaxf(vm[2], vm[3]));
            mx = fmaxf(mx, __shfl_xor(mx, 16));
            mx = fmaxf(mx, __shfl_xor(mx, 32));
            const float mn = fmaxf(m_i[mt], mx);
            const float alpha = exp2f(m_i[mt] - mn);
            m_i[mt] = mn;

            f32x4 s4 = {0.0f, 0.0f, 0.0f, 0.0f};
#pragma unroll
            for (int t = 0; t < 8; ++t) {
                f32x4 p;
#pragma unroll
                for (int r = 0; r < 4; ++r) p[r] = exp2f(st[mt][t][r] - mn);
                s4 += p;
                pk[mt][t][0] = pkbf(p[0], p[1]);
                pk[mt][t][1] = pkbf(p[2], p[3]);
            }
            float sum = s4[0] + s4[1] + s4[2] + s4[3];
            sum += __shfl_xor(sum, 16);
            sum += __shfl_xor(sum, 32);
            l_i[mt] = l_i[mt] * alpha + sum;
#pragma unroll
            for (int dt = 0; dt < 4; ++dt)
#pragma unroll
                for (int r = 0; r < 4; ++r) oacc[mt][dt][r] *= alpha;
        }

        // ---- O^T += V^T.P^T : one K=32 MFMA covers two 16-j chunks ----
        const int gd = (l15 >> 1) & 3;       // V read swizzle term
#pragma unroll
        for (int cp = 0; cp < 4; ++cp) {     // panel = chunks 2cp, 2cp+1
#pragma unroll
            for (int dt = 0; dt < 4; ++dt) {
                const int base = (dt * 16 + l15) * 32 + ((quad & 1) << 2);
                union { bf16x8 v; u64 d[2]; } vf;
                vf.d[0] = *(const u64*)&Vs[cp][base + (((quad >> 1) ^ gd) << 3)];
                vf.d[1] = *(const u64*)&Vs[cp][base + (((2 + (quad >> 1)) ^ gd) << 3)];
#pragma unroll
                for (int mt = 0; mt < 2; ++mt) {
                    union { bf16x8 v; u32 uw[4]; } pf;
                    pf.uw[0] = pk[mt][2 * cp][0];
                    pf.uw[1] = pk[mt][2 * cp][1];
                    pf.uw[2] = pk[mt][2 * cp + 1][0];
                    pf.uw[3] = pk[mt][2 * cp + 1][1];
                    oacc[mt][dt] = __builtin_amdgcn_mfma_f32_16x16x32_bf16(
                        vf.v, pf.v, oacc[mt][dt], 0, 0, 0);
                }
            }
        }
    }

    // ---- finalize: /l, packed 8B stores, (B,L,D) bf16 for the O-proj ----
#pragma unroll
    for (int mt = 0; mt < 2; ++mt) {
        const float inv = 1.0f / l_i[mt];
        const int l = l0 + w * 32 + mt * 16 + l15;
        u16* ob = out + ((size_t)(b * Lc + l)) * Dc + h * HDc;
#pragma unroll
        for (int dt = 0; dt < 4; ++dt) {
            uint2 pr;
            pr.x = pkbf(oacc[mt][dt][0] * inv, oacc[mt][dt][1] * inv);
            pr.y = pkbf(oacc[mt][dt][2] * inv, oacc[mt][dt][3] * inv);
            *(uint2*)&ob[dt * 16 + quad * 4] = pr;
        }
    }
}

// ---------------------------------------------------------------------------
// Output projection: d_out(fp32) = attn(bf16) @ Wo^T + bo. grid (32, 8).
// ---------------------------------------------------------------------------
__global__ __launch_bounds__(256) void gemm_o_bf16(
    const u16* __restrict__ Ab, const u16* __restrict__ Wob,
    const float* __restrict__ bo, float* __restrict__ out)
{
    __shared__ __attribute__((aligned(16))) u16 As[128 * 32];
    __shared__ __attribute__((aligned(16))) u16 Bs[128 * 32];
    const int row0 = blockIdx.x << 7;
    const int col0 = blockIdx.y << 7;

    f32x4 acc[4][4];
#pragma unroll
    for (int i = 0; i < 4; ++i)
#pragma unroll
        for (int j = 0; j < 4; ++j)
#pragma unroll
            for (int r = 0; r < 4; ++r) acc[i][j][r] = 0.0f;

    gemm128_body(Ab, Wob, row0, col0, Dc, acc, As, Bs);

    const int tid = threadIdx.x;
    const int w = tid >> 6, lane = tid & 63;
    const int l15 = lane & 15, quad = lane >> 4;
    const int wm = (w & 1) << 6, wn = (w >> 1) << 6;

#pragma unroll
    for (int j = 0; j < 4; ++j) {
        const int n = col0 + wn + j * 16 + l15;
        const float bj = bo[n];
#pragma unroll
        for (int i = 0; i < 4; ++i)
#pragma unroll
            for (int r = 0; r < 4; ++r) {
                const int m = row0 + wm + i * 16 + quad * 4 + r;
                out[(size_t)m * Dc + n] = acc[i][j][r] + bj;
            }
    }
}

extern "C" void kernel_launch(void* const* d_in, const int* in_sizes, int n_in,
                              void* d_out, int out_size, void* d_ws, size_t ws_size,
                              hipStream_t stream)
{
    const float* query = (const float*)d_in[0];
    const float* Wq = (const float*)d_in[1];
    const float* bq = (const float*)d_in[2];
    const float* Wk = (const float*)d_in[3];
    const float* bk = (const float*)d_in[4];
    const float* Wv = (const float*)d_in[5];
    const float* bv = (const float*)d_in[6];
    const float* Wo = (const float*)d_in[7];
    const float* bo = (const float*)d_in[8];

    // ws layout (u16 elems): xb 4.19M | wq/wk/wv/wo 1.05M ea | q | k | vt | a
    u16* ws = (u16*)d_ws;
    const size_t nX = (size_t)Bc * Lc * Dc;      // 4,194,304
    const size_t nW = (size_t)Dc * Dc;           // 1,048,576
    u16* xb  = ws;
    u16* wqb = xb + nX;
    u16* wkb = wqb + nW;
    u16* wvb = wkb + nW;
    u16* wob = wvb + nW;
    u16* q_w = wob + nW;
    u16* k_w = q_w + nX;
    u16* vt_w = k_w + nX;
    u16* a_w = vt_w + nX;

    cast_bf16<<<dim3(8192), 256, 0, stream>>>(query, Wq, Wk, Wv, Wo,
                                              xb, wqb, wkb, wvb, wob);
    gemm_qkv_bf16<<<dim3(32, 8, 3), 256, 0, stream>>>(xb, wqb, wkb, wvb,
                                                      bq, bk, bv, q_w, k_w, vt_w);
    attn_mfma<<<dim3(1024), 128, 0, stream>>>(q_w, k_w, vt_w, a_w);
    gemm_o_bf16<<<dim3(32, 8), 256, 0, stream>>>(a_w, wob, bo, (float*)d_out);
}